// Round 14
// baseline (123.046 us; speedup 1.0000x reference)
//
#include <hip/hip_runtime.h>
#include <hip/hip_bf16.h>

using bf16x8 = __attribute__((ext_vector_type(8))) short;
using f32x4  = __attribute__((ext_vector_type(4))) float;

constexpr int CH  = 64;
constexpr int HW  = 11;
constexpr int NP  = 121;
constexpr int PPW = 14;            // padded pos-grid row width
constexpr int NROW = 182;          // padded rows (13*14)
constexpr int ICL = 76;            // ic stride (ush): 152B = 38 banks, 2-way max
constexpr int IMG_USH = NROW * ICL;        // 13832 ush = 27664 B live
constexpr int IMG_I4  = IMG_USH / 8;       // 1729 int4 (27664 = 1729*16)
constexpr int IMG_P   = 14336;             // padded stride: 28 x 1024B segments
constexpr int NSEG    = 28;
constexpr int NO  = 7168;          // padded o rows (112 oc * 64 ic)
constexpr float EPS = 1e-5f;

__device__ __forceinline__ f32x4 MFMA(bf16x8 a, bf16x8 b, f32x4 c) {
    return __builtin_amdgcn_mfma_f32_16x16x32_bf16(a, b, c, 0, 0, 0);
}

// ---- pool (+fused prep): stats, img dump, Bg, Aprep/Beta ----
__global__ __launch_bounds__(256) void pool_kernel(
    const float* __restrict__ x_in,
    const float* __restrict__ gw, const float* __restrict__ gb,
    const float* __restrict__ bng, const float* __restrict__ bnb,
    const float* __restrict__ bnm, const float* __restrict__ bnv,
    unsigned short* __restrict__ img,   // [1024][IMG_P]
    unsigned short* __restrict__ Bg,    // [1024][512]
    unsigned short* __restrict__ Aprep, float* __restrict__ Beta)
{
    __shared__ alignas(16) unsigned short xsT[IMG_USH];  // 27664 B
    __shared__ float xh[2][128];
    __shared__ float xhp[2][2][128];

    const int phys = blockIdx.x;
    const int b = (phys & 7) * 128 + (phys >> 3);   // XCD-chunked
    const int t = threadIdx.x, lane = t & 63, wave = t >> 6;
    const float* xb = x_in + (size_t)b * (CH * NP);
    unsigned short* ib = img + (size_t)b * IMG_P;

    // fused prep: block handles o-rows [phys*7, phys*7+7), threads 0..27
    if (t < 28) {
        int o = phys * 7 + (t >> 2);
        int jgp = t & 3;
        float inv = 0.f, beta = 0.f;
        if (o < 6400) {
            inv  = bng[o] * rsqrtf(bnv[o] + EPS);
            beta = (gb[o] - bnm[o]) * inv + bnb[o];
        }
        if (jgp == 0) Beta[o] = beta;
        int tile = o >> 4, lr = o & 15;
        bf16x8 f;
        #pragma unroll
        for (int r = 0; r < 8; ++r) {
            int k = jgp * 8 + r;
            float v = (o < 6400 && k < 18) ? gw[(size_t)o * 18 + k] * inv : 0.f;
            __hip_bfloat16 h = __float2bfloat16(v);
            f[r] = *(short*)&h;
        }
        ((bf16x8*)Aprep)[tile * 64 + jgp * 16 + lr] = f;
    }

    for (int i = t; i < IMG_USH / 2; i += 256) ((unsigned int*)xsT)[i] = 0u;
    __syncthreads();

    {   // coalesced fp32 loads (lane->pos), bf16 scatter (2-way banks max)
        int p = (wave & 1) * 64 + lane, ich = wave >> 1;
        if (p < NP) {
            int pp = (p / HW + 1) * PPW + (p % HW + 1);
            float s = 0.f, m = -INFINITY;
            const float* xc = xb + (ich * 32) * NP + p;
            #pragma unroll 8
            for (int q = 0; q < 32; ++q) {
                float v = xc[q * NP];
                s += v; m = fmaxf(m, v);
                __hip_bfloat16 h = __float2bfloat16(v);
                xsT[pp * ICL + ich * 32 + q] = *(unsigned short*)&h;
            }
            xhp[ich][0][p] = s;
            xhp[ich][1][p] = m;
        }
    }
    __syncthreads();
    if (t < NP) {
        xh[0][t] = (xhp[0][0][t] + xhp[1][0][t]) * (1.f / 64.f);
        xh[1][t] = fmaxf(xhp[0][1][t], xhp[1][1][t]);
    }
    __syncthreads();

    // Bg[tap(16)][k(32)] zero-padded gen-B matrix
    for (int i = t; i < 512; i += 256) {
        int tap = i >> 5, k = i & 31;
        float val = 0.f;
        if (tap < 9 && k < 18) {
            int ci = k / 9, o9 = k - ci * 9, u = o9 / 3, v = o9 - u * 3;
            int kh = tap / 3, kw = tap - kh * 3;
            val = xh[ci][(4 * kh + u) * HW + (4 * kw + v)];
        }
        __hip_bfloat16 h = __float2bfloat16(val);
        Bg[b * 512 + i] = *(unsigned short*)&h;
    }

    // linear dump LDS -> img
    for (int i = t; i < IMG_I4; i += 256)
        ((int4*)ib)[i] = ((const int4*)xsT)[i];
}

// ---- main: 512 thr; wave = N-tile, B-frags in regs; loop 2 chunks ----
__global__ __launch_bounds__(512, 4) void hsi_main(
    const unsigned short* __restrict__ img,
    const unsigned short* __restrict__ Bg,
    const unsigned short* __restrict__ Aprep,
    const float* __restrict__ Beta,
    float* __restrict__ out)
{
    __shared__ alignas(16) unsigned short xs[IMG_P];             // 28672 B
    __shared__ alignas(16) unsigned short strip[2][18 * 64 * 8]; // 36864 B
    // total 65536 B -> 2 blocks/CU (16 waves, 4/SIMD)

    const int phys = blockIdx.x;
    const int L = (phys & 7) * 512 + (phys >> 3);   // XCD-chunked bijection
    const int b = L >> 2, d = L & 3;                // sample, chunk-pair
    const int t = threadIdx.x;
    const int lane = t & 63, wave = t >> 6;
    const int lrow = lane & 15, jg = lane >> 4;

    // 1) async stage img -> xs (global_load_lds w=16, wave-uniform dest)
    {
        const unsigned short* ib = img + (size_t)b * IMG_P;
        #pragma unroll
        for (int i = 0; i < 4; ++i) {
            int seg = wave + i * 8;
            if (seg < NSEG)
                __builtin_amdgcn_global_load_lds(
                    (const __attribute__((address_space(1))) void*)(ib + seg * 512 + lane * 8),
                    (__attribute__((address_space(3))) void*)(xs + seg * 512),
                    16, 0, 0);
        }
    }

    // 2) gen-B fragment
    const bf16x8 Bgen = *(const bf16x8*)(Bg + b * 512 + lrow * 32 + jg * 8);

    // 3) gen: waves 0-3 -> strip[0], waves 4-7 -> strip[1]; batched loads
    const int cl = wave >> 2;
    const int genchunk = d * 2 + cl;
    unsigned short* sp = strip[cl];
    const int tl0 = (wave & 3) * 14;
    #pragma unroll
    for (int bat = 0; bat < 2; ++bat) {
        bf16x8 Ar[7];
        float4 Br[7];
        #pragma unroll
        for (int j = 0; j < 7; ++j) {
            int tG = genchunk * 56 + tl0 + bat * 7 + j;   // global gen tile (<448)
            Ar[j] = *(const bf16x8*)(Aprep + ((size_t)tG * 64 + lane) * 8);
            Br[j] = *(const float4*)(Beta + (size_t)tG * 16 + jg * 4);
        }
        #pragma unroll
        for (int j = 0; j < 7; ++j) {
            int tl = tl0 + bat * 7 + j;                // chunk-local tile (0..55)
            f32x4 acc{};
            acc = MFMA(Ar[j], Bgen, acc);
            if (lrow < 9) {                            // C col = tap = lrow
                float v0 = fmaxf(acc[0] + Br[j].x, 0.f);
                float v1 = fmaxf(acc[1] + Br[j].y, 0.f);
                float v2 = fmaxf(acc[2] + Br[j].z, 0.f);
                float v3 = fmaxf(acc[3] + Br[j].w, 0.f);
                __hip_bfloat162 p01 = __float22bfloat162_rn(make_float2(v0, v1));
                __hip_bfloat162 p23 = __float22bfloat162_rn(make_float2(v2, v3));
                uint2 pk;
                pk.x = *(unsigned int*)&p01;
                pk.y = *(unsigned int*)&p23;
                int oc_l = tl >> 2, icb = tl & 3;
                int h   = icb >> 1;                    // k-half
                int jgr = (icb & 1) * 2 + (jg >> 1);   // reader k-group
                // slot: low4 ^= jgr<<2 spreads jg-groups across bank sets
                int slot = jgr * 16 + (oc_l ^ lrow ^ (jgr << 2));
                *(uint2*)(sp + ((lrow * 2 + h) * 64 + slot) * 8 + (jg & 1) * 4) = pk;
            }
        }
    }

    __syncthreads();   // drains async staging (vmcnt) + gen writes; only barrier

    // 4) B-frags: wave owns ONE 16-pos N-tile; 18 reads ONCE into registers
    const int p  = wave * 16 + lrow;
    const int pc = p > 120 ? 120 : p;
    const int base = (pc / HW) * PPW + (pc % HW);
    const char* xbp = (const char*)xs + base * (ICL * 2) + jg * 16;
    bf16x8 Bf[18];
    #pragma unroll
    for (int tap = 0; tap < 9; ++tap) {
        const int boff = ((tap / 3) * PPW + (tap % 3)) * (ICL * 2);
        Bf[tap * 2 + 0] = *(const bf16x8*)(xbp + boff);
        Bf[tap * 2 + 1] = *(const bf16x8*)(xbp + boff + 64);
    }

    // 5) chunk loop: A-frags from strip (XOR slots incl jg-spread), 18 MFMAs each
    float* ob = out + (size_t)b * 100 * NP;
    const int laneb2 = (lane ^ ((lane >> 4) << 2)) * 16;   // jg-spread un-swizzle
    #pragma unroll
    for (int q = 0; q < 2; ++q) {
        const char* spb = (const char*)strip[q];
        const int chunk = d * 2 + q;
        f32x4 acc{};
        #pragma unroll
        for (int tap = 0; tap < 9; ++tap) {
            const int av = laneb2 ^ (tap * 16);
            #pragma unroll
            for (int h = 0; h < 2; ++h) {
                bf16x8 Af = *(const bf16x8*)(spb + (tap * 2 + h) * 1024 + av);
                acc = MFMA(Af, Bf[tap * 2 + h], acc);
            }
        }
        #pragma unroll
        for (int ri = 0; ri < 4; ++ri) {
            int row = jg * 4 + ri;            // oc-local; rows 14,15 = next chunk
            int oc = chunk * 14 + row;
            if (row < 14 && oc < 100 && p < NP) ob[oc * NP + p] = acc[ri];
        }
    }
}

extern "C" void kernel_launch(void* const* d_in, const int* in_sizes, int n_in,
                              void* d_out, int out_size, void* d_ws, size_t ws_size,
                              hipStream_t stream) {
    const float* x  = (const float*)d_in[0];
    const float* gw = (const float*)d_in[1];
    const float* gb = (const float*)d_in[2];
    const float* bg = (const float*)d_in[3];
    const float* bb = (const float*)d_in[4];
    const float* bm = (const float*)d_in[5];
    const float* bv = (const float*)d_in[6];
    float* out = (float*)d_out;

    // ws: Aprep 458752 | Beta 28672 | Bg 1048576 | img 1024*28672  (~30.9 MiB)
    unsigned short* Aprep = (unsigned short*)d_ws;
    float* Beta = (float*)((char*)d_ws + 458752);
    unsigned short* Bgm = (unsigned short*)((char*)d_ws + 487424);
    unsigned short* img = (unsigned short*)((char*)d_ws + 1536000);

    pool_kernel<<<1024, 256, 0, stream>>>(x, gw, gb, bg, bb, bm, bv,
                                          img, Bgm, Aprep, Beta);
    hsi_main<<<1024 * 4, 512, 0, stream>>>(img, Bgm, Aprep, Beta, out);
}

// Round 15
// 69.355 us; speedup vs baseline: 1.7742x; 1.7742x over previous
//
#include <hip/hip_runtime.h>
#include <hip/hip_bf16.h>

using bf16x8 = __attribute__((ext_vector_type(8))) short;
using f32x4  = __attribute__((ext_vector_type(4))) float;

constexpr int CH  = 64;
constexpr int HW  = 11;
constexpr int NP  = 121;
constexpr int PPW = 14;            // padded pos-grid row width
constexpr int NROW = 182;          // padded rows (13*14)
constexpr int ICL = 72;            // ic stride (ush): 144B rows, 16B-ALIGNED (R14 lesson)
constexpr int IMG_USH = NROW * ICL;        // 13104 ush live
constexpr int IMG_I4  = IMG_USH / 8;       // 1638 int4
constexpr int IMG_P   = 13312;             // padded stride: 26 x 1024B segments
constexpr int NSEG    = 26;
constexpr int NO  = 7168;          // padded o rows (112 oc * 64 ic)
constexpr float EPS = 1e-5f;

__device__ __forceinline__ f32x4 MFMA(bf16x8 a, bf16x8 b, f32x4 c) {
    return __builtin_amdgcn_mfma_f32_16x16x32_bf16(a, b, c, 0, 0, 0);
}

// ---- pool (+fused prep): stats, img dump, Bg, Aprep/Beta ----
__global__ __launch_bounds__(256) void pool_kernel(
    const float* __restrict__ x_in,
    const float* __restrict__ gw, const float* __restrict__ gb,
    const float* __restrict__ bng, const float* __restrict__ bnb,
    const float* __restrict__ bnm, const float* __restrict__ bnv,
    unsigned short* __restrict__ img,   // [1024][IMG_P]
    unsigned short* __restrict__ Bg,    // [1024][512]
    unsigned short* __restrict__ Aprep, float* __restrict__ Beta)
{
    __shared__ alignas(16) unsigned short xsT[IMG_USH];  // 26208 B
    __shared__ float xh[2][128];
    __shared__ float xhp[2][2][128];

    const int phys = blockIdx.x;
    const int b = (phys & 7) * 128 + (phys >> 3);   // XCD-chunked
    const int t = threadIdx.x, lane = t & 63, wave = t >> 6;
    const float* xb = x_in + (size_t)b * (CH * NP);
    unsigned short* ib = img + (size_t)b * IMG_P;

    // fused prep: block handles o-rows [phys*7, phys*7+7), threads 0..27
    if (t < 28) {
        int o = phys * 7 + (t >> 2);
        int jgp = t & 3;
        float inv = 0.f, beta = 0.f;
        if (o < 6400) {
            inv  = bng[o] * rsqrtf(bnv[o] + EPS);
            beta = (gb[o] - bnm[o]) * inv + bnb[o];
        }
        if (jgp == 0) Beta[o] = beta;
        int tile = o >> 4, lr = o & 15;
        bf16x8 f;
        #pragma unroll
        for (int r = 0; r < 8; ++r) {
            int k = jgp * 8 + r;
            float v = (o < 6400 && k < 18) ? gw[(size_t)o * 18 + k] * inv : 0.f;
            __hip_bfloat16 h = __float2bfloat16(v);
            f[r] = *(short*)&h;
        }
        ((bf16x8*)Aprep)[tile * 64 + jgp * 16 + lr] = f;
    }

    for (int i = t; i < IMG_USH / 2; i += 256) ((unsigned int*)xsT)[i] = 0u;
    __syncthreads();

    {   // coalesced fp32 loads (lane->pos), bf16 scatter (2-way banks max)
        int p = (wave & 1) * 64 + lane, ich = wave >> 1;
        if (p < NP) {
            int pp = (p / HW + 1) * PPW + (p % HW + 1);
            float s = 0.f, m = -INFINITY;
            const float* xc = xb + (ich * 32) * NP + p;
            #pragma unroll 8
            for (int q = 0; q < 32; ++q) {
                float v = xc[q * NP];
                s += v; m = fmaxf(m, v);
                __hip_bfloat16 h = __float2bfloat16(v);
                xsT[pp * ICL + ich * 32 + q] = *(unsigned short*)&h;
            }
            xhp[ich][0][p] = s;
            xhp[ich][1][p] = m;
        }
    }
    __syncthreads();
    if (t < NP) {
        xh[0][t] = (xhp[0][0][t] + xhp[1][0][t]) * (1.f / 64.f);
        xh[1][t] = fmaxf(xhp[0][1][t], xhp[1][1][t]);
    }
    __syncthreads();

    // Bg[tap(16)][k(32)] zero-padded gen-B matrix
    for (int i = t; i < 512; i += 256) {
        int tap = i >> 5, k = i & 31;
        float val = 0.f;
        if (tap < 9 && k < 18) {
            int ci = k / 9, o9 = k - ci * 9, u = o9 / 3, v = o9 - u * 3;
            int kh = tap / 3, kw = tap - kh * 3;
            val = xh[ci][(4 * kh + u) * HW + (4 * kw + v)];
        }
        __hip_bfloat16 h = __float2bfloat16(val);
        Bg[b * 512 + i] = *(unsigned short*)&h;
    }

    // linear dump LDS -> img
    for (int i = t; i < IMG_I4; i += 256)
        ((int4*)ib)[i] = ((const int4*)xsT)[i];
}

// ---- main: 512 thr; wave = N-tile, B-frags in regs; loop 2 chunks ----
__global__ __launch_bounds__(512, 4) void hsi_main(
    const unsigned short* __restrict__ img,
    const unsigned short* __restrict__ Bg,
    const unsigned short* __restrict__ Aprep,
    const float* __restrict__ Beta,
    float* __restrict__ out)
{
    __shared__ alignas(16) unsigned short xs[IMG_P];             // 26624 B
    __shared__ alignas(16) unsigned short strip[2][18 * 64 * 8]; // 36864 B
    // total 63488 B -> 2 blocks/CU (16 waves, 4/SIMD)

    const int phys = blockIdx.x;
    const int L = (phys & 7) * 512 + (phys >> 3);   // XCD-chunked bijection
    const int b = L >> 2, d = L & 3;                // sample, chunk-pair
    const int t = threadIdx.x;
    const int lane = t & 63, wave = t >> 6;
    const int lrow = lane & 15, jg = lane >> 4;

    // 1) async stage img -> xs (global_load_lds w=16, wave-uniform dest)
    {
        const unsigned short* ib = img + (size_t)b * IMG_P;
        #pragma unroll
        for (int i = 0; i < 4; ++i) {
            int seg = wave + i * 8;
            if (seg < NSEG)
                __builtin_amdgcn_global_load_lds(
                    (const __attribute__((address_space(1))) void*)(ib + seg * 512 + lane * 8),
                    (__attribute__((address_space(3))) void*)(xs + seg * 512),
                    16, 0, 0);
        }
    }

    // 2) gen-B fragment
    const bf16x8 Bgen = *(const bf16x8*)(Bg + b * 512 + lrow * 32 + jg * 8);

    // 3) gen: waves 0-3 -> strip[0], waves 4-7 -> strip[1]; batched loads
    const int cl = wave >> 2;
    const int genchunk = d * 2 + cl;
    unsigned short* sp = strip[cl];
    const int tl0 = (wave & 3) * 14;
    #pragma unroll
    for (int bat = 0; bat < 2; ++bat) {
        bf16x8 Ar[7];
        float4 Br[7];
        #pragma unroll
        for (int j = 0; j < 7; ++j) {
            int tG = genchunk * 56 + tl0 + bat * 7 + j;   // global gen tile (<448)
            Ar[j] = *(const bf16x8*)(Aprep + ((size_t)tG * 64 + lane) * 8);
            Br[j] = *(const float4*)(Beta + (size_t)tG * 16 + jg * 4);
        }
        #pragma unroll
        for (int j = 0; j < 7; ++j) {
            int tl = tl0 + bat * 7 + j;                // chunk-local tile (0..55)
            f32x4 acc{};
            acc = MFMA(Ar[j], Bgen, acc);
            if (lrow < 9) {                            // C col = tap = lrow
                float v0 = fmaxf(acc[0] + Br[j].x, 0.f);
                float v1 = fmaxf(acc[1] + Br[j].y, 0.f);
                float v2 = fmaxf(acc[2] + Br[j].z, 0.f);
                float v3 = fmaxf(acc[3] + Br[j].w, 0.f);
                __hip_bfloat162 p01 = __float22bfloat162_rn(make_float2(v0, v1));
                __hip_bfloat162 p23 = __float22bfloat162_rn(make_float2(v2, v3));
                uint2 pk;
                pk.x = *(unsigned int*)&p01;
                pk.y = *(unsigned int*)&p23;
                int oc_l = tl >> 2, icb = tl & 3;
                int h   = icb >> 1;                    // k-half
                int jgr = (icb & 1) * 2 + (jg >> 1);   // reader k-group
                // slot low4 ^= jgr<<2: spreads the 4 jg-groups across bank sets
                int slot = jgr * 16 + (oc_l ^ lrow ^ (jgr << 2));
                *(uint2*)(sp + ((lrow * 2 + h) * 64 + slot) * 8 + (jg & 1) * 4) = pk;
            }
        }
    }

    __syncthreads();   // drains async staging (vmcnt) + gen writes; only barrier

    // 4) B-frags: wave owns ONE 16-pos N-tile; 18 reads ONCE into registers
    const int p  = wave * 16 + lrow;
    const int pc = p > 120 ? 120 : p;
    const int base = (pc / HW) * PPW + (pc % HW);
    const char* xbp = (const char*)xs + base * (ICL * 2) + jg * 16;
    bf16x8 Bf[18];
    #pragma unroll
    for (int tap = 0; tap < 9; ++tap) {
        const int boff = ((tap / 3) * PPW + (tap % 3)) * (ICL * 2);
        Bf[tap * 2 + 0] = *(const bf16x8*)(xbp + boff);
        Bf[tap * 2 + 1] = *(const bf16x8*)(xbp + boff + 64);
    }

    // 5) chunk loop: A-frags from strip (XOR slots incl jg-spread), 18 MFMAs each
    float* ob = out + (size_t)b * 100 * NP;
    const int laneb2 = (lane ^ ((lane >> 4) << 2)) * 16;   // jg-spread un-swizzle
    __builtin_amdgcn_s_setprio(1);                         // T5: favor MFMA waves
    #pragma unroll
    for (int q = 0; q < 2; ++q) {
        const char* spb = (const char*)strip[q];
        const int chunk = d * 2 + q;
        f32x4 acc{};
        #pragma unroll
        for (int tap = 0; tap < 9; ++tap) {
            const int av = laneb2 ^ (tap * 16);
            #pragma unroll
            for (int h = 0; h < 2; ++h) {
                bf16x8 Af = *(const bf16x8*)(spb + (tap * 2 + h) * 1024 + av);
                acc = MFMA(Af, Bf[tap * 2 + h], acc);
            }
        }
        __builtin_amdgcn_s_setprio(0);
        #pragma unroll
        for (int ri = 0; ri < 4; ++ri) {
            int row = jg * 4 + ri;            // oc-local; rows 14,15 = next chunk
            int oc = chunk * 14 + row;
            if (row < 14 && oc < 100 && p < NP) ob[oc * NP + p] = acc[ri];
        }
        if (q == 0) __builtin_amdgcn_s_setprio(1);
    }
}

extern "C" void kernel_launch(void* const* d_in, const int* in_sizes, int n_in,
                              void* d_out, int out_size, void* d_ws, size_t ws_size,
                              hipStream_t stream) {
    const float* x  = (const float*)d_in[0];
    const float* gw = (const float*)d_in[1];
    const float* gb = (const float*)d_in[2];
    const float* bg = (const float*)d_in[3];
    const float* bb = (const float*)d_in[4];
    const float* bm = (const float*)d_in[5];
    const float* bv = (const float*)d_in[6];
    float* out = (float*)d_out;

    // ws: Aprep 458752 | Beta 28672 | Bg 1048576 | img 1024*26624  (~28.8 MiB)
    unsigned short* Aprep = (unsigned short*)d_ws;
    float* Beta = (float*)((char*)d_ws + 458752);
    unsigned short* Bgm = (unsigned short*)((char*)d_ws + 487424);
    unsigned short* img = (unsigned short*)((char*)d_ws + 1536000);

    pool_kernel<<<1024, 256, 0, stream>>>(x, gw, gb, bg, bb, bm, bv,
                                          img, Bgm, Aprep, Beta);
    hsi_main<<<1024 * 4, 512, 0, stream>>>(img, Bgm, Aprep, Beta, out);
}

// Round 16
// 66.761 us; speedup vs baseline: 1.8431x; 1.0389x over previous
//
#include <hip/hip_runtime.h>
#include <hip/hip_bf16.h>

using bf16x8 = __attribute__((ext_vector_type(8))) short;
using f32x4  = __attribute__((ext_vector_type(4))) float;

constexpr int CH  = 64;
constexpr int HW  = 11;
constexpr int NP  = 121;
constexpr int PPW = 14;            // padded pos-grid row width
constexpr int NROW = 182;          // padded rows (13*14)
constexpr int ICL = 72;            // ic stride (ush): 144B rows, 16B-aligned
constexpr int IMG_USH = NROW * ICL;        // 13104 ush live
constexpr int IMG_I4  = IMG_USH / 8;       // 1638 int4
constexpr int IMG_P   = 13312;             // padded stride: 26 x 1024B segments
constexpr int NSEG    = 26;
constexpr int NO  = 7168;          // padded o rows (112 oc * 64 ic)
constexpr float EPS = 1e-5f;

__device__ __forceinline__ f32x4 MFMA(bf16x8 a, bf16x8 b, f32x4 c) {
    return __builtin_amdgcn_mfma_f32_16x16x32_bf16(a, b, c, 0, 0, 0);
}

// ---- pool (+fused prep): stats, img dump, Bg, Aprep/Beta ----
__global__ __launch_bounds__(256) void pool_kernel(
    const float* __restrict__ x_in,
    const float* __restrict__ gw, const float* __restrict__ gb,
    const float* __restrict__ bng, const float* __restrict__ bnb,
    const float* __restrict__ bnm, const float* __restrict__ bnv,
    unsigned short* __restrict__ img,   // [1024][IMG_P]
    unsigned short* __restrict__ Bg,    // [1024][512]
    unsigned short* __restrict__ Aprep, float* __restrict__ Beta)
{
    __shared__ alignas(16) unsigned short xsT[IMG_USH];  // 26208 B
    __shared__ float xh[2][128];
    __shared__ float xhp[2][2][128];

    const int phys = blockIdx.x;
    const int b = (phys & 7) * 128 + (phys >> 3);   // XCD-chunked
    const int t = threadIdx.x, lane = t & 63, wave = t >> 6;
    const float* xb = x_in + (size_t)b * (CH * NP);
    unsigned short* ib = img + (size_t)b * IMG_P;

    // fused prep: block handles o-rows [phys*7, phys*7+7), threads 0..27
    if (t < 28) {
        int o = phys * 7 + (t >> 2);
        int jgp = t & 3;
        float inv = 0.f, beta = 0.f;
        if (o < 6400) {
            inv  = bng[o] * rsqrtf(bnv[o] + EPS);
            beta = (gb[o] - bnm[o]) * inv + bnb[o];
        }
        if (jgp == 0) Beta[o] = beta;
        int tile = o >> 4, lr = o & 15;
        bf16x8 f;
        #pragma unroll
        for (int r = 0; r < 8; ++r) {
            int k = jgp * 8 + r;
            float v = (o < 6400 && k < 18) ? gw[(size_t)o * 18 + k] * inv : 0.f;
            __hip_bfloat16 h = __float2bfloat16(v);
            f[r] = *(short*)&h;
        }
        ((bf16x8*)Aprep)[tile * 64 + jgp * 16 + lr] = f;
    }

    for (int i = t; i < IMG_USH / 2; i += 256) ((unsigned int*)xsT)[i] = 0u;
    __syncthreads();

    {   // coalesced fp32 loads (lane->pos), bf16 scatter (2-way banks max)
        int p = (wave & 1) * 64 + lane, ich = wave >> 1;
        if (p < NP) {
            int pp = (p / HW + 1) * PPW + (p % HW + 1);
            float s = 0.f, m = -INFINITY;
            const float* xc = xb + (ich * 32) * NP + p;
            #pragma unroll 8
            for (int q = 0; q < 32; ++q) {
                float v = xc[q * NP];
                s += v; m = fmaxf(m, v);
                __hip_bfloat16 h = __float2bfloat16(v);
                xsT[pp * ICL + ich * 32 + q] = *(unsigned short*)&h;
            }
            xhp[ich][0][p] = s;
            xhp[ich][1][p] = m;
        }
    }
    __syncthreads();
    if (t < NP) {
        xh[0][t] = (xhp[0][0][t] + xhp[1][0][t]) * (1.f / 64.f);
        xh[1][t] = fmaxf(xhp[0][1][t], xhp[1][1][t]);
    }
    __syncthreads();

    // Bg[tap(16)][k(32)] zero-padded gen-B matrix
    for (int i = t; i < 512; i += 256) {
        int tap = i >> 5, k = i & 31;
        float val = 0.f;
        if (tap < 9 && k < 18) {
            int ci = k / 9, o9 = k - ci * 9, u = o9 / 3, v = o9 - u * 3;
            int kh = tap / 3, kw = tap - kh * 3;
            val = xh[ci][(4 * kh + u) * HW + (4 * kw + v)];
        }
        __hip_bfloat16 h = __float2bfloat16(val);
        Bg[b * 512 + i] = *(unsigned short*)&h;
    }

    // linear dump LDS -> img
    for (int i = t; i < IMG_I4; i += 256)
        ((int4*)ib)[i] = ((const int4*)xsT)[i];
}

// ---- main: 512 thr; wave = N-tile, B-frags PINNED in regs; loop 2 chunks ----
__global__ __launch_bounds__(512, 4) void hsi_main(
    const unsigned short* __restrict__ img,
    const unsigned short* __restrict__ Bg,
    const unsigned short* __restrict__ Aprep,
    const float* __restrict__ Beta,
    float* __restrict__ out)
{
    __shared__ alignas(16) unsigned short xs[IMG_P];             // 26624 B
    __shared__ alignas(16) unsigned short strip[2][18 * 64 * 8]; // 36864 B
    // total 63488 B -> 2 blocks/CU (16 waves, 4/SIMD)

    const int phys = blockIdx.x;
    const int L = (phys & 7) * 512 + (phys >> 3);   // XCD-chunked bijection
    const int b = L >> 2, d = L & 3;                // sample, chunk-pair
    const int t = threadIdx.x;
    const int lane = t & 63, wave = t >> 6;
    const int lrow = lane & 15, jg = lane >> 4;

    // 1) async stage img -> xs (global_load_lds w=16, wave-uniform dest)
    {
        const unsigned short* ib = img + (size_t)b * IMG_P;
        #pragma unroll
        for (int i = 0; i < 4; ++i) {
            int seg = wave + i * 8;
            if (seg < NSEG)
                __builtin_amdgcn_global_load_lds(
                    (const __attribute__((address_space(1))) void*)(ib + seg * 512 + lane * 8),
                    (__attribute__((address_space(3))) void*)(xs + seg * 512),
                    16, 0, 0);
        }
    }

    // 2) gen-B fragment
    const bf16x8 Bgen = *(const bf16x8*)(Bg + b * 512 + lrow * 32 + jg * 8);

    // 3) gen: waves 0-3 -> strip[0], waves 4-7 -> strip[1]; batched loads
    const int cl = wave >> 2;
    const int genchunk = d * 2 + cl;
    unsigned short* sp = strip[cl];
    const int tl0 = (wave & 3) * 14;
    #pragma unroll
    for (int bat = 0; bat < 2; ++bat) {
        bf16x8 Ar[7];
        float4 Br[7];
        #pragma unroll
        for (int j = 0; j < 7; ++j) {
            int tG = genchunk * 56 + tl0 + bat * 7 + j;   // global gen tile (<448)
            Ar[j] = *(const bf16x8*)(Aprep + ((size_t)tG * 64 + lane) * 8);
            Br[j] = *(const float4*)(Beta + (size_t)tG * 16 + jg * 4);
        }
        #pragma unroll
        for (int j = 0; j < 7; ++j) {
            int tl = tl0 + bat * 7 + j;                // chunk-local tile (0..55)
            f32x4 acc{};
            acc = MFMA(Ar[j], Bgen, acc);
            if (lrow < 9) {                            // C col = tap = lrow
                float v0 = fmaxf(acc[0] + Br[j].x, 0.f);
                float v1 = fmaxf(acc[1] + Br[j].y, 0.f);
                float v2 = fmaxf(acc[2] + Br[j].z, 0.f);
                float v3 = fmaxf(acc[3] + Br[j].w, 0.f);
                __hip_bfloat162 p01 = __float22bfloat162_rn(make_float2(v0, v1));
                __hip_bfloat162 p23 = __float22bfloat162_rn(make_float2(v2, v3));
                uint2 pk;
                pk.x = *(unsigned int*)&p01;
                pk.y = *(unsigned int*)&p23;
                int oc_l = tl >> 2, icb = tl & 3;
                int h   = icb >> 1;                    // k-half
                int jgr = (icb & 1) * 2 + (jg >> 1);   // reader k-group
                int slot = (jgr * 16 + oc_l) ^ lrow;   // R13-verified mapping
                *(uint2*)(sp + ((lrow * 2 + h) * 64 + slot) * 8 + (jg & 1) * 4) = pk;
            }
        }
    }

    __syncthreads();   // drains async staging (vmcnt) + gen writes; only barrier

    // 4) B-frags: wave owns ONE 16-pos N-tile; 18 reads ONCE, PINNED live
    const int p  = wave * 16 + lrow;
    const int pc = p > 120 ? 120 : p;
    const int base = (pc / HW) * PPW + (pc % HW);
    const char* xbp = (const char*)xs + base * (ICL * 2) + jg * 16;
    bf16x8 Bf[18];
    #pragma unroll
    for (int tap = 0; tap < 9; ++tap) {
        const int boff = ((tap / 3) * PPW + (tap % 3)) * (ICL * 2);
        Bf[tap * 2 + 0] = *(const bf16x8*)(xbp + boff);
        Bf[tap * 2 + 1] = *(const bf16x8*)(xbp + boff + 64);
    }
    // Opaque pin: forces all 18 fragments (72 VGPR) to stay materialized —
    // without this the compiler re-reads LDS inside the chunk loop (R13: VGPR=52).
    asm volatile("" :
        "+v"(Bf[0]), "+v"(Bf[1]), "+v"(Bf[2]), "+v"(Bf[3]), "+v"(Bf[4]),
        "+v"(Bf[5]), "+v"(Bf[6]), "+v"(Bf[7]), "+v"(Bf[8]), "+v"(Bf[9]),
        "+v"(Bf[10]), "+v"(Bf[11]), "+v"(Bf[12]), "+v"(Bf[13]), "+v"(Bf[14]),
        "+v"(Bf[15]), "+v"(Bf[16]), "+v"(Bf[17]));

    // 5) chunk loop: A-frags from strip (conflict-free XOR slots), 18 MFMAs each
    float* ob = out + (size_t)b * 100 * NP;
    const int laneb = lane * 16;
    #pragma unroll
    for (int q = 0; q < 2; ++q) {
        const char* spb = (const char*)strip[q];
        const int chunk = d * 2 + q;
        f32x4 acc{};
        #pragma unroll
        for (int tap = 0; tap < 9; ++tap) {
            const int av = laneb ^ (tap * 16);
            #pragma unroll
            for (int h = 0; h < 2; ++h) {
                bf16x8 Af = *(const bf16x8*)(spb + (tap * 2 + h) * 1024 + av);
                acc = MFMA(Af, Bf[tap * 2 + h], acc);
            }
        }
        #pragma unroll
        for (int ri = 0; ri < 4; ++ri) {
            int row = jg * 4 + ri;            // oc-local; rows 14,15 = next chunk
            int oc = chunk * 14 + row;
            if (row < 14 && oc < 100 && p < NP) ob[oc * NP + p] = acc[ri];
        }
    }
}

extern "C" void kernel_launch(void* const* d_in, const int* in_sizes, int n_in,
                              void* d_out, int out_size, void* d_ws, size_t ws_size,
                              hipStream_t stream) {
    const float* x  = (const float*)d_in[0];
    const float* gw = (const float*)d_in[1];
    const float* gb = (const float*)d_in[2];
    const float* bg = (const float*)d_in[3];
    const float* bb = (const float*)d_in[4];
    const float* bm = (const float*)d_in[5];
    const float* bv = (const float*)d_in[6];
    float* out = (float*)d_out;

    // ws: Aprep 458752 | Beta 28672 | Bg 1048576 | img 1024*26624  (~28.8 MiB)
    unsigned short* Aprep = (unsigned short*)d_ws;
    float* Beta = (float*)((char*)d_ws + 458752);
    unsigned short* Bgm = (unsigned short*)((char*)d_ws + 487424);
    unsigned short* img = (unsigned short*)((char*)d_ws + 1536000);

    pool_kernel<<<1024, 256, 0, stream>>>(x, gw, gb, bg, bb, bm, bv,
                                          img, Bgm, Aprep, Beta);
    hsi_main<<<1024 * 4, 512, 0, stream>>>(img, Bgm, Aprep, Beta, out);
}